// Round 1
// baseline (815.216 us; speedup 1.0000x reference)
//
#include <hip/hip_runtime.h>
#include <hip/hip_cooperative_groups.h>
#include <cstdint>
#include <cstddef>

namespace cg = cooperative_groups;

#define BATCH 64
#define NIN   1024
#define CIN   256
#define NC    32
#define NJC   16     // j-blocks per batch (64 j each)
#define JCH   64
#define T_EPS 1e-7f
#define CT_S  72     // cT row stride in u16 (144 B)

typedef __attribute__((ext_vector_type(8))) short short8;   // 8 bf16 = 4 VGPR
typedef __attribute__((ext_vector_type(4))) float floatx4;  // MFMA 16x16 acc

__device__ __forceinline__ unsigned short bf16rne(float f) {
  unsigned int u = __float_as_uint(f);
  u += 0x7FFFu + ((u >> 16) & 1u);
  return (unsigned short)(u >> 16);
}
__device__ __forceinline__ float bf2f(unsigned short h) {
  return __uint_as_float(((unsigned int)h) << 16);
}
// swizzled u16 index into the 64x256 LDS x-tile (16B chunks XOR-permuted per j)
__device__ __forceinline__ int xsw(int j, int c) {
  return j * 256 + ((((c >> 3) ^ (j & 7) ^ ((j >> 3) & 7)) << 3) | (c & 7));
}

struct K2S {
  float ys[CIN];       // 1 KB
  float sred[8][32];   // 1 KB
  float os[NC];        // 128 B
};
union USH {
  float4 red[4][64];            // 4 KB   (phase 0 colsum)
  unsigned short cT[NC * CT_S]; // 4.5 KB (fused softmax coeffs)
  K2S k2;                       // 2.2 KB (squash phases)
};

// ---- K2 core: s = ys@W_i -> squash -> wt(bf16) or out --------------------
// assumes u->k2.ys is populated and the block is synced.
__device__ __forceinline__ void k2_core(int i, int b, int t,
                                        const unsigned short* __restrict__ Wi,
                                        USH* u,
                                        unsigned short* __restrict__ wtout,
                                        float* __restrict__ outg,
                                        bool writeOut) {
  const unsigned short* Wis = Wi + (size_t)i * CIN * NC;
  {
    const int k = t & 31, g = t >> 5;
    float ps = 0.f;
    #pragma unroll
    for (int cc = 0; cc < 32; ++cc) {
      int c = g * 32 + ((cc + g * 4) & 31);  // rotated start: conflict-free ys reads
      ps += u->k2.ys[c] * bf2f(Wis[c * NC + k]);
    }
    u->k2.sred[g][k] = ps;
  }
  __syncthreads();
  const int k = t & 31;
  float s = 0.f;
  #pragma unroll
  for (int g = 0; g < 8; ++g) s += u->k2.sred[g][k];
  float s2 = s * s;
  #pragma unroll
  for (int m = 1; m < 32; m <<= 1) s2 += __shfl_xor(s2, m);
  float o = s * rsqrtf(s2 + T_EPS);
  if (writeOut) {
    if (t < 32) outg[((size_t)b * NC + i) * 32 + t] = o;
    __syncthreads();
  } else {
    if (t < 32) u->k2.os[t] = o;
    __syncthreads();
    float acc = 0.f;
    const short8* wrow = (const short8*)(Wis + (size_t)t * NC);
    #pragma unroll
    for (int k8 = 0; k8 < 4; ++k8) {
      short8 wv = wrow[k8];
      #pragma unroll
      for (int e = 0; e < 8; ++e)
        acc += u->k2.os[k8 * 8 + e] * bf2f((unsigned short)wv[e]);
    }
    wtout[((size_t)b * NC + i) * CIN + t] = bf16rne(acc);
    __syncthreads();
  }
}

// ---- fused routing iteration: L = wt@x^T -> softmax(i) -> y = c@x --------
// x tile already resident (swizzled) in xs.
__device__ __forceinline__ void fused_iter(int b, int t,
                                           const unsigned short* xs, USH* u,
                                           const unsigned short* __restrict__ wt,
                                           unsigned short* __restrict__ yo) {
  const int w = t >> 6, l16 = t & 15, q = (t >> 4) & 3;
  const int jloc = w * 16 + l16;
  const unsigned short* wrow = wt + (size_t)b * NC * CIN;
  floatx4 accA0 = {0.f, 0.f, 0.f, 0.f}, accA1 = {0.f, 0.f, 0.f, 0.f};
  #pragma unroll
  for (int ks = 0; ks < 8; ++ks) {
    short8 bx = *(const short8*)&xs[xsw(jloc, ks * 32 + q * 8)];
    short8 a0 = *(const short8*)(wrow + (size_t)l16 * CIN + ks * 32 + q * 8);
    short8 a1 = *(const short8*)(wrow + (size_t)(16 + l16) * CIN + ks * 32 + q * 8);
    accA0 = __builtin_amdgcn_mfma_f32_16x16x32_bf16(a0, bx, accA0, 0, 0, 0);
    accA1 = __builtin_amdgcn_mfma_f32_16x16x32_bf16(a1, bx, accA1, 0, 0, 0);
  }
  {
    float m = accA0[0];
    #pragma unroll
    for (int r = 1; r < 4; ++r) m = fmaxf(m, accA0[r]);
    #pragma unroll
    for (int r = 0; r < 4; ++r) m = fmaxf(m, accA1[r]);
    m = fmaxf(m, __shfl_xor(m, 16));
    m = fmaxf(m, __shfl_xor(m, 32));
    float e0[4], e1[4], s = 0.f;
    #pragma unroll
    for (int r = 0; r < 4; ++r) {
      e0[r] = __expf(accA0[r] - m);
      e1[r] = __expf(accA1[r] - m);
      s += e0[r] + e1[r];
    }
    s += __shfl_xor(s, 16);
    s += __shfl_xor(s, 32);
    float rs = 1.f / s;
    #pragma unroll
    for (int r = 0; r < 4; ++r) {
      u->cT[(q * 4 + r) * CT_S + jloc]      = bf16rne(e0[r] * rs);
      u->cT[(16 + q * 4 + r) * CT_S + jloc] = bf16rne(e1[r] * rs);
    }
  }
  __syncthreads();
  const int cw = w * 64;
  floatx4 accB[2][4];
  #pragma unroll
  for (int h = 0; h < 2; ++h)
    #pragma unroll
    for (int ct = 0; ct < 4; ++ct) accB[h][ct] = (floatx4){0.f, 0.f, 0.f, 0.f};
  #pragma unroll
  for (int ks = 0; ks < 2; ++ks) {
    short8 ca0 = *(const short8*)&u->cT[l16 * CT_S + ks * 32 + q * 8];
    short8 ca1 = *(const short8*)&u->cT[(16 + l16) * CT_S + ks * 32 + q * 8];
    #pragma unroll
    for (int ct = 0; ct < 4; ++ct) {
      const int c = cw + ct * 16 + l16;
      short8 xf;
      #pragma unroll
      for (int e = 0; e < 8; ++e)
        xf[e] = (short)xs[xsw(ks * 32 + q * 8 + e, c)];
      accB[0][ct] = __builtin_amdgcn_mfma_f32_16x16x32_bf16(ca0, xf, accB[0][ct], 0, 0, 0);
      accB[1][ct] = __builtin_amdgcn_mfma_f32_16x16x32_bf16(ca1, xf, accB[1][ct], 0, 0, 0);
    }
  }
  #pragma unroll
  for (int h = 0; h < 2; ++h)
    #pragma unroll
    for (int ct = 0; ct < 4; ++ct)
      #pragma unroll
      for (int r = 0; r < 4; ++r) {
        int i = h * 16 + q * 4 + r;
        int c = cw + ct * 16 + l16;
        yo[i * CIN + c] = bf16rne(accB[h][ct][r]);
      }
  __syncthreads();   // cT reuse safety for subsequent phases
}

// ---- the whole pipeline as ONE cooperative kernel ------------------------
// grid (jc=16, b=64) = 1024 blocks = 256 CU x 4 blocks/CU (exactly co-resident).
// Block (jc,b): owns x-tile [b, jc*64 .. jc*64+63, :] in LDS for the whole
// run, and owns capsules i = 2jc, 2jc+1 of batch b in the squash phases.
__global__ __launch_bounds__(256, 4) void k_all(const float* __restrict__ x,
                                                const float* __restrict__ W,
                                                unsigned short* __restrict__ Wi,
                                                float* __restrict__ y0p,
                                                unsigned short* __restrict__ wtb,
                                                unsigned short* __restrict__ ypart,
                                                float* __restrict__ outg) {
  cg::grid_group grid = cg::this_grid();
  const int jc = blockIdx.x, b = blockIdx.y, t = threadIdx.x;
  __shared__ unsigned short xs[64 * 256];  // 32 KB, swizzled, lives all phases
  __shared__ USH u;                        // 4.5 KB, phase-aliased

  // ---- phase 0: x fp32 -> bf16 swizzled LDS + colsum partials + Wi -------
  {
    const int jj = t >> 6, c4 = t & 63;
    const float4* xg = (const float4*)(x + ((size_t)(b * NIN + jc * JCH)) * CIN);
    float4 acc = make_float4(0.f, 0.f, 0.f, 0.f);
    #pragma unroll
    for (int jr = 0; jr < 16; ++jr) {
      int j = jr * 4 + jj;
      float4 v = xg[j * 64 + c4];
      acc.x += v.x; acc.y += v.y; acc.z += v.z; acc.w += v.w;
      ushort4 h;
      h.x = bf16rne(v.x); h.y = bf16rne(v.y);
      h.z = bf16rne(v.z); h.w = bf16rne(v.w);
      // c = c4*4: low 3 bits are 0 or 4 -> aligned half-chunk, xsw-consistent
      *(ushort4*)&xs[xsw(j, c4 * 4)] = h;
    }
    u.red[jj][c4] = acc;
    if (b == 0) {
      // build Wi rows for i = jc*2, jc*2+1 ; thread t <-> c
      #pragma unroll
      for (int i2 = 0; i2 < 2; ++i2) {
        int i = jc * 2 + i2;
        const float4* wsrc = (const float4*)(W + (size_t)t * 1024 + i * 32);
        unsigned short* wdst = Wi + ((size_t)i * CIN + t) * NC;
        #pragma unroll
        for (int k4 = 0; k4 < 8; ++k4) {
          float4 v = wsrc[k4];
          ushort4 h;
          h.x = bf16rne(v.x); h.y = bf16rne(v.y);
          h.z = bf16rne(v.z); h.w = bf16rne(v.w);
          *(ushort4*)&wdst[k4 * 4] = h;
        }
      }
    }
    __syncthreads();
    if (t < 64) {
      float4 s = u.red[0][t];
      #pragma unroll
      for (int p = 1; p < 4; ++p) {
        s.x += u.red[p][t].x; s.y += u.red[p][t].y;
        s.z += u.red[p][t].z; s.w += u.red[p][t].w;
      }
      *(float4*)&y0p[(b * NJC + jc) * CIN + t * 4] = s;
    }
  }
  grid.sync();  // y0p + Wi visible grid-wide

  // ---- phase 1: iter-0  y = colsum/32 @ W_i -> squash -> wt --------------
  {
    float a = 0.f;
    #pragma unroll
    for (int p = 0; p < NJC; ++p) a += y0p[(b * NJC + p) * CIN + t];
    u.k2.ys[t] = a * (1.f / 32.f);
    __syncthreads();
    k2_core(jc * 2,     b, t, Wi, &u, wtb, nullptr, false);
    k2_core(jc * 2 + 1, b, t, Wi, &u, wtb, nullptr, false);
  }
  grid.sync();  // wt visible

  // ---- phase 2: routing iter 1 (x tile still in LDS!) --------------------
  fused_iter(b, t, xs, &u, wtb, ypart + ((size_t)(b * NJC + jc)) * NC * CIN);
  grid.sync();  // ypart visible

  // ---- phase 3: reduce ypart -> squash -> wt -----------------------------
  #pragma unroll 1
  for (int ii = 0; ii < 2; ++ii) {
    int i = jc * 2 + ii;
    float a = 0.f;
    #pragma unroll
    for (int p = 0; p < NJC; ++p)
      a += bf2f(ypart[(((size_t)(b * NJC + p)) * NC + i) * CIN + t]);
    u.k2.ys[t] = a;
    __syncthreads();
    k2_core(i, b, t, Wi, &u, wtb, nullptr, false);
  }
  grid.sync();  // wt v2 visible

  // ---- phase 4: routing iter 2 -------------------------------------------
  fused_iter(b, t, xs, &u, wtb, ypart + ((size_t)(b * NJC + jc)) * NC * CIN);
  grid.sync();  // ypart v2 visible

  // ---- phase 5: reduce -> squash -> out ----------------------------------
  #pragma unroll 1
  for (int ii = 0; ii < 2; ++ii) {
    int i = jc * 2 + ii;
    float a = 0.f;
    #pragma unroll
    for (int p = 0; p < NJC; ++p)
      a += bf2f(ypart[(((size_t)(b * NJC + p)) * NC + i) * CIN + t]);
    u.k2.ys[t] = a;
    __syncthreads();
    k2_core(i, b, t, Wi, &u, nullptr, outg, true);
  }
}

// ======================= fallback path (proven 6-kernel) ====================

__global__ __launch_bounds__(256) void k_convert(const float* __restrict__ x,
                                                 const float* __restrict__ W,
                                                 unsigned short* __restrict__ xb,
                                                 unsigned short* __restrict__ Wi,
                                                 float* __restrict__ y0p) {
  const int jc = blockIdx.x, b = blockIdx.y, t = threadIdx.x;
  const int jj = t >> 6, c4 = t & 63;
  __shared__ float4 red[4][64];
  const float4* xg = (const float4*)(x + ((size_t)(b * NIN + jc * JCH)) * CIN);
  ushort4* xo = (ushort4*)(xb + ((size_t)(b * NIN + jc * JCH)) * CIN);
  float4 acc = make_float4(0.f, 0.f, 0.f, 0.f);
  #pragma unroll
  for (int jr = 0; jr < 16; ++jr) {
    int j = jr * 4 + jj;
    float4 v = xg[j * 64 + c4];
    acc.x += v.x; acc.y += v.y; acc.z += v.z; acc.w += v.w;
    ushort4 h;
    h.x = bf16rne(v.x); h.y = bf16rne(v.y);
    h.z = bf16rne(v.z); h.w = bf16rne(v.w);
    xo[j * 64 + c4] = h;
  }
  red[jj][c4] = acc;
  if (b == 0) {
    #pragma unroll
    for (int i2 = 0; i2 < 2; ++i2) {
      int i = jc * 2 + i2;
      const float4* wsrc = (const float4*)(W + (size_t)t * 1024 + i * 32);
      unsigned short* wdst = Wi + ((size_t)i * CIN + t) * NC;
      #pragma unroll
      for (int k4 = 0; k4 < 8; ++k4) {
        float4 v = wsrc[k4];
        ushort4 h;
        h.x = bf16rne(v.x); h.y = bf16rne(v.y);
        h.z = bf16rne(v.z); h.w = bf16rne(v.w);
        *(ushort4*)&wdst[k4 * 4] = h;
      }
    }
  }
  __syncthreads();
  if (t < 64) {
    float4 s = red[0][t];
    #pragma unroll
    for (int p = 1; p < 4; ++p) {
      s.x += red[p][t].x; s.y += red[p][t].y;
      s.z += red[p][t].z; s.w += red[p][t].w;
    }
    *(float4*)&y0p[(b * NJC + jc) * CIN + t * 4] = s;
  }
}

template <int MODE>
__global__ __launch_bounds__(256) void k_post(const void* __restrict__ yin,
                                              const unsigned short* __restrict__ Wi,
                                              unsigned short* __restrict__ wtout,
                                              float* __restrict__ outg) {
  const int i = blockIdx.x, b = blockIdx.y, t = threadIdx.x;
  __shared__ float ys[CIN];
  __shared__ float sred[8][32];
  __shared__ float os[NC];
  float a = 0.f;
  if (MODE == 0) {
    const float* y0p = (const float*)yin;
    #pragma unroll
    for (int p = 0; p < NJC; ++p) a += y0p[(b * NJC + p) * CIN + t];
    a *= (1.f / 32.f);
  } else {
    const unsigned short* yp = (const unsigned short*)yin;
    #pragma unroll
    for (int p = 0; p < NJC; ++p)
      a += bf2f(yp[(((size_t)(b * NJC + p)) * NC + i) * CIN + t]);
  }
  ys[t] = a;
  __syncthreads();
  const unsigned short* Wis = Wi + (size_t)i * CIN * NC;
  {
    const int k = t & 31, g = t >> 5;
    float ps = 0.f;
    #pragma unroll
    for (int cc = 0; cc < 32; ++cc) {
      int c = g * 32 + ((cc + g * 4) & 31);
      ps += ys[c] * bf2f(Wis[c * NC + k]);
    }
    sred[g][k] = ps;
  }
  __syncthreads();
  const int k = t & 31;
  float s = 0.f;
  #pragma unroll
  for (int g = 0; g < 8; ++g) s += sred[g][k];
  float s2 = s * s;
  #pragma unroll
  for (int m = 1; m < 32; m <<= 1) s2 += __shfl_xor(s2, m);
  float o = s * rsqrtf(s2 + T_EPS);
  if (MODE == 2) {
    if (t < 32) outg[((size_t)b * NC + i) * 32 + t] = o;
  } else {
    if (t < 32) os[t] = o;
    __syncthreads();
    float acc = 0.f;
    const short8* wrow = (const short8*)(Wis + (size_t)t * NC);
    #pragma unroll
    for (int k8 = 0; k8 < 4; ++k8) {
      short8 wv = wrow[k8];
      #pragma unroll
      for (int e = 0; e < 8; ++e)
        acc += os[k8 * 8 + e] * bf2f((unsigned short)wv[e]);
    }
    wtout[((size_t)b * NC + i) * CIN + t] = bf16rne(acc);
  }
}

__global__ __launch_bounds__(256, 4) void k_fused(const unsigned short* __restrict__ xb,
                                                  const unsigned short* __restrict__ wt,
                                                  unsigned short* __restrict__ ypart) {
  const int jc = blockIdx.x, b = blockIdx.y, t = threadIdx.x;
  __shared__ unsigned short xs[64 * 256];
  __shared__ USH u;
  {
    const short8* xg =
        (const short8*)(xb + ((size_t)(b * NIN) + (size_t)jc * JCH) * CIN);
    #pragma unroll
    for (int it = 0; it < 8; ++it) {
      int f = it * 256 + t;
      int j = f >> 5, ch = f & 31;
      *(short8*)&xs[xsw(j, ch * 8)] = xg[f];
    }
  }
  __syncthreads();
  fused_iter(b, t, xs, &u, wt, ypart + ((size_t)(b * NJC + jc)) * NC * CIN);
}

// ===========================================================================

extern "C" void kernel_launch(void* const* d_in, const int* in_sizes, int n_in,
                              void* d_out, int out_size, void* d_ws, size_t ws_size,
                              hipStream_t stream) {
  (void)in_sizes; (void)n_in; (void)out_size; (void)ws_size;
  const float* x = (const float*)d_in[0];
  const float* W = (const float*)d_in[1];
  float* out = (float*)d_out;
  char* ws = (char*)d_ws;
  // ws: xb 32MiB (fallback only) | wt 1MiB | ypart 16MiB | y0p 1MiB | Wi 512KiB
  unsigned short* xbuf  = (unsigned short*)ws;
  unsigned short* wtb   = (unsigned short*)(ws + (32ull << 20));
  unsigned short* ypart = (unsigned short*)(ws + (33ull << 20));
  float*          y0p   = (float*)(ws + (49ull << 20));
  unsigned short* Wi    = (unsigned short*)(ws + (50ull << 20));

  dim3 gfuse(NJC, BATCH);     // (16, 64) = 1024 blocks = exact co-residency
  dim3 gpost(NC, BATCH);      // (32, 64)

  const float* xa = x;
  const float* Wa = W;
  unsigned short* Wia = Wi;
  float* y0pa = y0p;
  unsigned short* wtba = wtb;
  unsigned short* yparta = ypart;
  float* outa = out;
  void* args[] = {(void*)&xa, (void*)&Wa, (void*)&Wia, (void*)&y0pa,
                  (void*)&wtba, (void*)&yparta, (void*)&outa};
  hipError_t e = hipLaunchCooperativeKernel((const void*)k_all, gfuse, dim3(256),
                                            args, 0, stream);
  if (e != hipSuccess) {
    (void)hipGetLastError();  // clear sticky error, fall back to 6-kernel path
    k_convert<<<gfuse, 256, 0, stream>>>(x, W, xbuf, Wi, y0p);
    k_post<0><<<gpost, 256, 0, stream>>>(y0p, Wi, wtb, nullptr);
    k_fused<<<gfuse, 256, 0, stream>>>(xbuf, wtb, ypart);
    k_post<1><<<gpost, 256, 0, stream>>>(ypart, Wi, wtb, nullptr);
    k_fused<<<gfuse, 256, 0, stream>>>(xbuf, wtb, ypart);
    k_post<2><<<gpost, 256, 0, stream>>>(ypart, Wi, nullptr, out);
  }
}

// Round 2
// 235.254 us; speedup vs baseline: 3.4653x; 3.4653x over previous
//
#include <hip/hip_runtime.h>
#include <cstdint>
#include <cstddef>

#define BATCH 64
#define NIN   1024
#define CIN   256
#define NC    32
#define NJC   16
#define JCH   64
#define T_EPS 1e-7f
#define CT_S  72     // cT row stride in u16 (144 B)
#define SCOPE_AGENT __HIP_MEMORY_SCOPE_AGENT

typedef __attribute__((ext_vector_type(8))) short short8;   // 8 bf16 = 4 VGPR
typedef __attribute__((ext_vector_type(4))) float floatx4;  // MFMA 16x16 acc

__device__ __forceinline__ unsigned short bf16rne(float f) {
  unsigned int u = __float_as_uint(f);
  u += 0x7FFFu + ((u >> 16) & 1u);
  return (unsigned short)(u >> 16);
}
__device__ __forceinline__ float bf2f(unsigned short h) {
  return __uint_as_float(((unsigned int)h) << 16);
}
// swizzled u16 index into a 64x256 LDS x-tile (16B chunks XOR-permuted per j)
__device__ __forceinline__ int xsw(int j, int c) {
  return j * 256 + ((((c >> 3) ^ (j & 7) ^ ((j >> 3) & 7)) << 3) | (c & 7));
}
// swizzled u16 index into the 32x256 LDS wt tile
__device__ __forceinline__ int wsw(int i, int c) {
  return i * 256 + ((((c >> 3) ^ (i & 7)) << 3) | (c & 7));
}

// coherent (agent-scope) accessors: bypass non-coherent L2 for cross-XCD data
__device__ __forceinline__ float cload(const float* p) {
  return __hip_atomic_load(p, __ATOMIC_RELAXED, SCOPE_AGENT);
}
__device__ __forceinline__ void cstore(float* p, float v) {
  __hip_atomic_store(p, v, __ATOMIC_RELAXED, SCOPE_AGENT);
}
__device__ __forceinline__ unsigned int cloadu(const unsigned int* p) {
  return __hip_atomic_load(p, __ATOMIC_RELAXED, SCOPE_AGENT);
}
__device__ __forceinline__ void cstoreu(unsigned int* p, unsigned int v) {
  __hip_atomic_store(p, v, __ATOMIC_RELAXED, SCOPE_AGENT);
}

struct K2S { float ys[CIN]; float sred[8][32]; float os[NC]; };
struct SQS { float ys2[8][CIN]; float os2[8][NC]; };
union USH {
  float4 red[4][64];            // 4 KB   (phase 0 colsum)
  unsigned short cT[NC * CT_S]; // 4.5 KB (fused softmax coeffs)
  K2S k2;                       // 2.2 KB (fallback squash)
  SQS sq;                       // 9 KB   (persistent-kernel squash)
};

// 4-block-per-b barrier. flags[b] zeroed by hipMemsetAsync each launch;
// monotonic target = 4 * phase. Spin relaxed, one acquire on exit.
__device__ __forceinline__ void groupbar(unsigned int* flag, unsigned int target,
                                         int t) {
  __syncthreads();   // drains vmcnt -> all prior coherent stores complete
  if (t == 0) {
    __hip_atomic_fetch_add(flag, 1u, __ATOMIC_RELEASE, SCOPE_AGENT);
    while (__hip_atomic_load(flag, __ATOMIC_RELAXED, SCOPE_AGENT) < target)
      __builtin_amdgcn_s_sleep(2);
    (void)__hip_atomic_load(flag, __ATOMIC_ACQUIRE, SCOPE_AGENT);
  }
  __syncthreads();
}

// ---- routing j-loop over the block's 4 resident 64-j tiles -----------------
// wt read from swizzled LDS; accB accumulates across tiles (fp32, 256 j).
__device__ __forceinline__ void jloop_iter(int t, const unsigned short* xs,
                                           const unsigned short* wts, USH& u,
                                           floatx4 accB[2][4]) {
  const int w = t >> 6, l16 = t & 15, q = (t >> 4) & 3;
  const int jloc = w * 16 + l16;
  #pragma unroll 1
  for (int tile = 0; tile < 4; ++tile) {
    const unsigned short* xt = xs + tile * 16384;
    floatx4 accA0 = {0.f, 0.f, 0.f, 0.f}, accA1 = {0.f, 0.f, 0.f, 0.f};
    #pragma unroll
    for (int ks = 0; ks < 8; ++ks) {
      short8 bx = *(const short8*)&xt[xsw(jloc, ks * 32 + q * 8)];
      short8 a0 = *(const short8*)&wts[wsw(l16, ks * 32 + q * 8)];
      short8 a1 = *(const short8*)&wts[wsw(16 + l16, ks * 32 + q * 8)];
      accA0 = __builtin_amdgcn_mfma_f32_16x16x32_bf16(a0, bx, accA0, 0, 0, 0);
      accA1 = __builtin_amdgcn_mfma_f32_16x16x32_bf16(a1, bx, accA1, 0, 0, 0);
    }
    {
      float m = accA0[0];
      #pragma unroll
      for (int r = 1; r < 4; ++r) m = fmaxf(m, accA0[r]);
      #pragma unroll
      for (int r = 0; r < 4; ++r) m = fmaxf(m, accA1[r]);
      m = fmaxf(m, __shfl_xor(m, 16));
      m = fmaxf(m, __shfl_xor(m, 32));
      float e0[4], e1[4], s = 0.f;
      #pragma unroll
      for (int r = 0; r < 4; ++r) {
        e0[r] = __expf(accA0[r] - m);
        e1[r] = __expf(accA1[r] - m);
        s += e0[r] + e1[r];
      }
      s += __shfl_xor(s, 16);
      s += __shfl_xor(s, 32);
      float rs = 1.f / s;
      #pragma unroll
      for (int r = 0; r < 4; ++r) {
        u.cT[(q * 4 + r) * CT_S + jloc]      = bf16rne(e0[r] * rs);
        u.cT[(16 + q * 4 + r) * CT_S + jloc] = bf16rne(e1[r] * rs);
      }
    }
    __syncthreads();
    const int cw = w * 64;
    #pragma unroll
    for (int ks = 0; ks < 2; ++ks) {
      short8 ca0 = *(const short8*)&u.cT[l16 * CT_S + ks * 32 + q * 8];
      short8 ca1 = *(const short8*)&u.cT[(16 + l16) * CT_S + ks * 32 + q * 8];
      #pragma unroll
      for (int ct = 0; ct < 4; ++ct) {
        const int c = cw + ct * 16 + l16;
        short8 xf;
        #pragma unroll
        for (int e = 0; e < 8; ++e)
          xf[e] = (short)xt[xsw(ks * 32 + q * 8 + e, c)];
        accB[0][ct] = __builtin_amdgcn_mfma_f32_16x16x32_bf16(ca0, xf, accB[0][ct], 0, 0, 0);
        accB[1][ct] = __builtin_amdgcn_mfma_f32_16x16x32_bf16(ca1, xf, accB[1][ct], 0, 0, 0);
      }
    }
    __syncthreads();  // cT reused next tile
  }
}

// ---- squash: s = ys2 @ Wi2 -> normalize -> wt (or final out) --------------
// Wi2 layout [ik][c] = [1024][256] bf16, ik = i*32+k. Block qb owns rows
// qb*256 .. qb*256+255 (i.e. i in [qb*8, qb*8+8)).
template <bool LAST>
__device__ __forceinline__ void squash_phase(int qb, int b, int t,
                                             const unsigned short* __restrict__ Wi2,
                                             unsigned int* __restrict__ wtx,
                                             float* __restrict__ outg, USH& u) {
  const int il = t >> 5, k = t & 31;
  float o;
  {
    const unsigned short* wrow = Wi2 + ((size_t)(qb * 256 + t)) * CIN;
    float s = 0.f;
    #pragma unroll 8
    for (int c8 = 0; c8 < 32; ++c8) {
      short8 wv = *(const short8*)&wrow[c8 * 8];
      #pragma unroll
      for (int e = 0; e < 8; ++e)
        s += u.sq.ys2[il][c8 * 8 + e] * bf2f((unsigned short)wv[e]);
    }
    float s2 = s * s;
    #pragma unroll
    for (int m = 1; m < 32; m <<= 1) s2 += __shfl_xor(s2, m);
    o = s * rsqrtf(s2 + T_EPS);
  }
  if (LAST) {
    outg[((size_t)b * NC + qb * 8 + il) * 32 + k] = o;
    return;
  }
  u.sq.os2[il][k] = o;
  __syncthreads();
  {
    float a[8];
    #pragma unroll
    for (int e = 0; e < 8; ++e) a[e] = 0.f;
    const unsigned short* wbase = Wi2 + ((size_t)(qb * 256 + il * 32)) * CIN + k * 8;
    #pragma unroll 8
    for (int kk = 0; kk < 32; ++kk) {
      short8 wv = *(const short8*)&wbase[(size_t)kk * CIN];
      float ok = u.sq.os2[il][kk];
      #pragma unroll
      for (int e = 0; e < 8; ++e) a[e] += ok * bf2f((unsigned short)wv[e]);
    }
    unsigned int* dst = wtx + (((size_t)b * NC + qb * 8 + il) * CIN + k * 8) / 2;
    #pragma unroll
    for (int m2 = 0; m2 < 4; ++m2)
      cstoreu(dst + m2, (unsigned int)bf16rne(a[2 * m2]) |
                        ((unsigned int)bf16rne(a[2 * m2 + 1]) << 16));
  }
}

// pull full wt[b] (all 32 i) into swizzled LDS
__device__ __forceinline__ void load_wts(int b, int t,
                                         const unsigned int* __restrict__ wtx,
                                         unsigned short* wts) {
  const int i = t >> 3, cb = (t & 7) * 32;
  const unsigned int* src = wtx + ((size_t)b * NC + i) * (CIN / 2) + cb / 2;
  #pragma unroll
  for (int m = 0; m < 4; ++m) {
    unsigned int v0 = cloadu(src + m * 4 + 0);
    unsigned int v1 = cloadu(src + m * 4 + 1);
    unsigned int v2 = cloadu(src + m * 4 + 2);
    unsigned int v3 = cloadu(src + m * 4 + 3);
    *(uint4*)&wts[wsw(i, cb + m * 8)] = make_uint4(v0, v1, v2, v3);
  }
}

// ---- persistent kernel: grid (4, 64) = 256 blocks = 1 block/CU ------------
// Block (qb, b): x rows [b, qb*256 .. qb*256+255, :] resident in LDS for all
// 3 routing iterations; capsules i in [qb*8, qb*8+8) in squash phases.
// Cross-block sync: per-b 4-block barrier on flags[b] (coherent, light).
__global__ __launch_bounds__(256, 1) void k_one(const float* __restrict__ x,
                                                const float* __restrict__ W,
                                                unsigned short* __restrict__ Wi2,
                                                float* __restrict__ csx,
                                                float* __restrict__ ypx,
                                                unsigned int* __restrict__ wtx,
                                                unsigned int* __restrict__ flags,
                                                float* __restrict__ outg) {
  const int qb = blockIdx.x, b = blockIdx.y, t = threadIdx.x;
  const int w = t >> 6;
  __shared__ unsigned short xs[4 * 16384];  // 128 KB: 4 swizzled 64x256 tiles
  __shared__ unsigned short wts[NC * CIN];  // 16 KB: swizzled wt
  __shared__ USH u;                         // 9 KB: phase-aliased

  // ---- ph0a: build Wi2 rows for this qb (identical-write safe across b) ---
  {
    unsigned short* wdst = Wi2 + ((size_t)(qb * 256 + t)) * CIN;
    #pragma unroll 4
    for (int c0 = 0; c0 < 32; ++c0) {
      short8 h;
      #pragma unroll
      for (int e = 0; e < 8; ++e)
        h[e] = (short)bf16rne(W[(size_t)(c0 * 8 + e) * 1024 + qb * 256 + t]);
      *(short8*)&wdst[c0 * 8] = h;
    }
  }
  // ---- ph0b: x fp32 -> bf16 swizzled LDS + colsum partials ----------------
  {
    const float4* xg = (const float4*)(x + ((size_t)b * NIN + qb * 256) * CIN);
    const int c4 = t & 63;
    float4 acc = make_float4(0.f, 0.f, 0.f, 0.f);
    #pragma unroll 8
    for (int it = 0; it < 64; ++it) {
      int j = it * 4 + w;  // 0..255 local
      float4 v = xg[(size_t)j * 64 + c4];
      acc.x += v.x; acc.y += v.y; acc.z += v.z; acc.w += v.w;
      ushort4 h;
      h.x = bf16rne(v.x); h.y = bf16rne(v.y);
      h.z = bf16rne(v.z); h.w = bf16rne(v.w);
      *(ushort4*)&xs[(j >> 6) * 16384 + xsw(j & 63, c4 * 4)] = h;
    }
    u.red[w][c4] = acc;
    __syncthreads();
    if (t < 64) {
      float4 s = u.red[0][t];
      #pragma unroll
      for (int p = 1; p < 4; ++p) {
        s.x += u.red[p][t].x; s.y += u.red[p][t].y;
        s.z += u.red[p][t].z; s.w += u.red[p][t].w;
      }
      float* dst = csx + ((size_t)b * 4 + qb) * CIN + t * 4;
      cstore(dst + 0, s.x); cstore(dst + 1, s.y);
      cstore(dst + 2, s.z); cstore(dst + 3, s.w);
    }
  }
  groupbar(flags + b, 4u * 1u, t);  // B1: csx visible within b-group

  // ---- iter 0: ys = colsum/32 (same for all i) -> squash -> wt ------------
  {
    float v = 0.f;
    #pragma unroll
    for (int q2 = 0; q2 < 4; ++q2)
      v += cload(&csx[((size_t)b * 4 + q2) * CIN + t]);
    v *= (1.f / 32.f);
    #pragma unroll
    for (int il = 0; il < 8; ++il) u.sq.ys2[il][t] = v;
  }
  __syncthreads();
  squash_phase<false>(qb, b, t, Wi2, wtx, nullptr, u);
  groupbar(flags + b, 4u * 2u, t);  // B2: wt0 visible

  // ---- iter 1 -------------------------------------------------------------
  load_wts(b, t, wtx, wts);
  __syncthreads();
  {
    floatx4 accB[2][4];
    #pragma unroll
    for (int h = 0; h < 2; ++h)
      #pragma unroll
      for (int ct = 0; ct < 4; ++ct) accB[h][ct] = (floatx4){0.f, 0.f, 0.f, 0.f};
    jloop_iter(t, xs, wts, u, accB);
    const int l16 = t & 15, q = (t >> 4) & 3;
    #pragma unroll
    for (int h = 0; h < 2; ++h)
      #pragma unroll
      for (int ct = 0; ct < 4; ++ct)
        #pragma unroll
        for (int r = 0; r < 4; ++r) {
          int i = h * 16 + q * 4 + r;
          int c = w * 64 + ct * 16 + l16;
          cstore(&ypx[(((size_t)b * 4 + qb) * NC + i) * CIN + c], accB[h][ct][r]);
        }
  }
  groupbar(flags + b, 4u * 3u, t);  // B3: y partials visible
  {
    #pragma unroll
    for (int il = 0; il < 8; ++il) {
      int i = qb * 8 + il;
      float v = 0.f;
      #pragma unroll
      for (int q2 = 0; q2 < 4; ++q2)
        v += cload(&ypx[(((size_t)b * 4 + q2) * NC + i) * CIN + t]);
      u.sq.ys2[il][t] = v;
    }
  }
  __syncthreads();
  squash_phase<false>(qb, b, t, Wi2, wtx, nullptr, u);
  groupbar(flags + b, 4u * 4u, t);  // B4: wt1 visible

  // ---- iter 2 -------------------------------------------------------------
  load_wts(b, t, wtx, wts);
  __syncthreads();
  {
    floatx4 accB[2][4];
    #pragma unroll
    for (int h = 0; h < 2; ++h)
      #pragma unroll
      for (int ct = 0; ct < 4; ++ct) accB[h][ct] = (floatx4){0.f, 0.f, 0.f, 0.f};
    jloop_iter(t, xs, wts, u, accB);
    const int l16 = t & 15, q = (t >> 4) & 3;
    #pragma unroll
    for (int h = 0; h < 2; ++h)
      #pragma unroll
      for (int ct = 0; ct < 4; ++ct)
        #pragma unroll
        for (int r = 0; r < 4; ++r) {
          int i = h * 16 + q * 4 + r;
          int c = w * 64 + ct * 16 + l16;
          cstore(&ypx[(((size_t)b * 4 + qb) * NC + i) * CIN + c], accB[h][ct][r]);
        }
  }
  groupbar(flags + b, 4u * 5u, t);  // B5: y partials visible
  {
    #pragma unroll
    for (int il = 0; il < 8; ++il) {
      int i = qb * 8 + il;
      float v = 0.f;
      #pragma unroll
      for (int q2 = 0; q2 < 4; ++q2)
        v += cload(&ypx[(((size_t)b * 4 + q2) * NC + i) * CIN + t]);
      u.sq.ys2[il][t] = v;
    }
  }
  __syncthreads();
  squash_phase<true>(qb, b, t, Wi2, nullptr, outg, u);
}

// ======================= fallback path (proven 6-kernel) ====================

__device__ __forceinline__ void fused_iter_old(int b, int t,
                                               const unsigned short* xs, USH* u,
                                               const unsigned short* __restrict__ wt,
                                               unsigned short* __restrict__ yo) {
  const int w = t >> 6, l16 = t & 15, q = (t >> 4) & 3;
  const int jloc = w * 16 + l16;
  const unsigned short* wrow = wt + (size_t)b * NC * CIN;
  floatx4 accA0 = {0.f, 0.f, 0.f, 0.f}, accA1 = {0.f, 0.f, 0.f, 0.f};
  #pragma unroll
  for (int ks = 0; ks < 8; ++ks) {
    short8 bx = *(const short8*)&xs[xsw(jloc, ks * 32 + q * 8)];
    short8 a0 = *(const short8*)(wrow + (size_t)l16 * CIN + ks * 32 + q * 8);
    short8 a1 = *(const short8*)(wrow + (size_t)(16 + l16) * CIN + ks * 32 + q * 8);
    accA0 = __builtin_amdgcn_mfma_f32_16x16x32_bf16(a0, bx, accA0, 0, 0, 0);
    accA1 = __builtin_amdgcn_mfma_f32_16x16x32_bf16(a1, bx, accA1, 0, 0, 0);
  }
  {
    float m = accA0[0];
    #pragma unroll
    for (int r = 1; r < 4; ++r) m = fmaxf(m, accA0[r]);
    #pragma unroll
    for (int r = 0; r < 4; ++r) m = fmaxf(m, accA1[r]);
    m = fmaxf(m, __shfl_xor(m, 16));
    m = fmaxf(m, __shfl_xor(m, 32));
    float e0[4], e1[4], s = 0.f;
    #pragma unroll
    for (int r = 0; r < 4; ++r) {
      e0[r] = __expf(accA0[r] - m);
      e1[r] = __expf(accA1[r] - m);
      s += e0[r] + e1[r];
    }
    s += __shfl_xor(s, 16);
    s += __shfl_xor(s, 32);
    float rs = 1.f / s;
    #pragma unroll
    for (int r = 0; r < 4; ++r) {
      u->cT[(q * 4 + r) * CT_S + jloc]      = bf16rne(e0[r] * rs);
      u->cT[(16 + q * 4 + r) * CT_S + jloc] = bf16rne(e1[r] * rs);
    }
  }
  __syncthreads();
  const int cw = w * 64;
  floatx4 accB[2][4];
  #pragma unroll
  for (int h = 0; h < 2; ++h)
    #pragma unroll
    for (int ct = 0; ct < 4; ++ct) accB[h][ct] = (floatx4){0.f, 0.f, 0.f, 0.f};
  #pragma unroll
  for (int ks = 0; ks < 2; ++ks) {
    short8 ca0 = *(const short8*)&u->cT[l16 * CT_S + ks * 32 + q * 8];
    short8 ca1 = *(const short8*)&u->cT[(16 + l16) * CT_S + ks * 32 + q * 8];
    #pragma unroll
    for (int ct = 0; ct < 4; ++ct) {
      const int c = cw + ct * 16 + l16;
      short8 xf;
      #pragma unroll
      for (int e = 0; e < 8; ++e)
        xf[e] = (short)xs[xsw(ks * 32 + q * 8 + e, c)];
      accB[0][ct] = __builtin_amdgcn_mfma_f32_16x16x32_bf16(ca0, xf, accB[0][ct], 0, 0, 0);
      accB[1][ct] = __builtin_amdgcn_mfma_f32_16x16x32_bf16(ca1, xf, accB[1][ct], 0, 0, 0);
    }
  }
  #pragma unroll
  for (int h = 0; h < 2; ++h)
    #pragma unroll
    for (int ct = 0; ct < 4; ++ct)
      #pragma unroll
      for (int r = 0; r < 4; ++r) {
        int i = h * 16 + q * 4 + r;
        int c = cw + ct * 16 + l16;
        yo[i * CIN + c] = bf16rne(accB[h][ct][r]);
      }
  __syncthreads();
}

__global__ __launch_bounds__(256) void k_convert(const float* __restrict__ x,
                                                 const float* __restrict__ W,
                                                 unsigned short* __restrict__ xb,
                                                 unsigned short* __restrict__ Wi,
                                                 float* __restrict__ y0p) {
  const int jc = blockIdx.x, b = blockIdx.y, t = threadIdx.x;
  const int jj = t >> 6, c4 = t & 63;
  __shared__ float4 red[4][64];
  const float4* xg = (const float4*)(x + ((size_t)(b * NIN + jc * JCH)) * CIN);
  ushort4* xo = (ushort4*)(xb + ((size_t)(b * NIN + jc * JCH)) * CIN);
  float4 acc = make_float4(0.f, 0.f, 0.f, 0.f);
  #pragma unroll
  for (int jr = 0; jr < 16; ++jr) {
    int j = jr * 4 + jj;
    float4 v = xg[j * 64 + c4];
    acc.x += v.x; acc.y += v.y; acc.z += v.z; acc.w += v.w;
    ushort4 h;
    h.x = bf16rne(v.x); h.y = bf16rne(v.y);
    h.z = bf16rne(v.z); h.w = bf16rne(v.w);
    xo[j * 64 + c4] = h;
  }
  red[jj][c4] = acc;
  if (b == 0) {
    #pragma unroll
    for (int i2 = 0; i2 < 2; ++i2) {
      int i = jc * 2 + i2;
      const float4* wsrc = (const float4*)(W + (size_t)t * 1024 + i * 32);
      unsigned short* wdst = Wi + ((size_t)i * CIN + t) * NC;
      #pragma unroll
      for (int k4 = 0; k4 < 8; ++k4) {
        float4 v = wsrc[k4];
        ushort4 h;
        h.x = bf16rne(v.x); h.y = bf16rne(v.y);
        h.z = bf16rne(v.z); h.w = bf16rne(v.w);
        *(ushort4*)&wdst[k4 * 4] = h;
      }
    }
  }
  __syncthreads();
  if (t < 64) {
    float4 s = red[0][t];
    #pragma unroll
    for (int p = 1; p < 4; ++p) {
      s.x += red[p][t].x; s.y += red[p][t].y;
      s.z += red[p][t].z; s.w += red[p][t].w;
    }
    *(float4*)&y0p[(b * NJC + jc) * CIN + t * 4] = s;
  }
}

template <int MODE>
__global__ __launch_bounds__(256) void k_post(const void* __restrict__ yin,
                                              const unsigned short* __restrict__ Wi,
                                              unsigned short* __restrict__ wtout,
                                              float* __restrict__ outg) {
  const int i = blockIdx.x, b = blockIdx.y, t = threadIdx.x;
  __shared__ float ys[CIN];
  __shared__ float sred[8][32];
  __shared__ float os[NC];
  float a = 0.f;
  if (MODE == 0) {
    const float* y0p = (const float*)yin;
    #pragma unroll
    for (int p = 0; p < NJC; ++p) a += y0p[(b * NJC + p) * CIN + t];
    a *= (1.f / 32.f);
  } else {
    const unsigned short* yp = (const unsigned short*)yin;
    #pragma unroll
    for (int p = 0; p < NJC; ++p)
      a += bf2f(yp[(((size_t)(b * NJC + p)) * NC + i) * CIN + t]);
  }
  ys[t] = a;
  __syncthreads();
  const unsigned short* Wis = Wi + (size_t)i * CIN * NC;
  {
    const int k = t & 31, g = t >> 5;
    float ps = 0.f;
    #pragma unroll
    for (int cc = 0; cc < 32; ++cc) {
      int c = g * 32 + ((cc + g * 4) & 31);
      ps += ys[c] * bf2f(Wis[c * NC + k]);
    }
    sred[g][k] = ps;
  }
  __syncthreads();
  const int k = t & 31;
  float s = 0.f;
  #pragma unroll
  for (int g = 0; g < 8; ++g) s += sred[g][k];
  float s2 = s * s;
  #pragma unroll
  for (int m = 1; m < 32; m <<= 1) s2 += __shfl_xor(s2, m);
  float o = s * rsqrtf(s2 + T_EPS);
  if (MODE == 2) {
    if (t < 32) outg[((size_t)b * NC + i) * 32 + t] = o;
  } else {
    if (t < 32) os[t] = o;
    __syncthreads();
    float acc = 0.f;
    const short8* wrow = (const short8*)(Wis + (size_t)t * NC);
    #pragma unroll
    for (int k8 = 0; k8 < 4; ++k8) {
      short8 wv = wrow[k8];
      #pragma unroll
      for (int e = 0; e < 8; ++e)
        acc += os[k8 * 8 + e] * bf2f((unsigned short)wv[e]);
    }
    wtout[((size_t)b * NC + i) * CIN + t] = bf16rne(acc);
  }
}

__global__ __launch_bounds__(256, 4) void k_fused(const unsigned short* __restrict__ xb,
                                                  const unsigned short* __restrict__ wt,
                                                  unsigned short* __restrict__ ypart) {
  const int jc = blockIdx.x, b = blockIdx.y, t = threadIdx.x;
  __shared__ unsigned short xs[64 * 256];
  __shared__ USH u;
  {
    const short8* xg =
        (const short8*)(xb + ((size_t)(b * NIN) + (size_t)jc * JCH) * CIN);
    #pragma unroll
    for (int it = 0; it < 8; ++it) {
      int f = it * 256 + t;
      int j = f >> 5, ch = f & 31;
      *(short8*)&xs[xsw(j, ch * 8)] = xg[f];
    }
  }
  __syncthreads();
  fused_iter_old(b, t, xs, &u, wt, ypart + ((size_t)(b * NJC + jc)) * NC * CIN);
}

// ===========================================================================

extern "C" void kernel_launch(void* const* d_in, const int* in_sizes, int n_in,
                              void* d_out, int out_size, void* d_ws, size_t ws_size,
                              hipStream_t stream) {
  (void)in_sizes; (void)n_in; (void)out_size; (void)ws_size;
  const float* x = (const float*)d_in[0];
  const float* W = (const float*)d_in[1];
  float* out = (float*)d_out;
  char* ws = (char*)d_ws;

  // new-path ws: Wi2 512K @0 | csx 256K @1M | ypx 8M @2M | wtx 1M @10M | flags @11M
  unsigned short* Wi2  = (unsigned short*)ws;
  float*          csx  = (float*)(ws + (1ull << 20));
  float*          ypx  = (float*)(ws + (2ull << 20));
  unsigned int*   wtx  = (unsigned int*)(ws + (10ull << 20));
  unsigned int*   flags = (unsigned int*)(ws + (11ull << 20));

  (void)hipMemsetAsync(flags, 0, BATCH * sizeof(unsigned int), stream);

  const float* xa = x;
  const float* Wa = W;
  unsigned short* Wi2a = Wi2;
  float* csxa = csx;
  float* ypxa = ypx;
  unsigned int* wtxa = wtx;
  unsigned int* flagsa = flags;
  float* outa = out;
  void* args[] = {(void*)&xa, (void*)&Wa, (void*)&Wi2a, (void*)&csxa,
                  (void*)&ypxa, (void*)&wtxa, (void*)&flagsa, (void*)&outa};
  hipError_t e = hipLaunchCooperativeKernel((const void*)k_one, dim3(4, BATCH),
                                            dim3(256), args, 0, stream);
  if (e != hipSuccess) {
    (void)hipGetLastError();  // clear sticky error; proven 6-kernel fallback
    unsigned short* xbuf  = (unsigned short*)ws;
    unsigned short* wtb   = (unsigned short*)(ws + (32ull << 20));
    unsigned short* ypart = (unsigned short*)(ws + (33ull << 20));
    float*          y0p   = (float*)(ws + (49ull << 20));
    unsigned short* Wi    = (unsigned short*)(ws + (50ull << 20));
    dim3 gfuse(NJC, BATCH);
    dim3 gpost(NC, BATCH);
    k_convert<<<gfuse, 256, 0, stream>>>(x, W, xbuf, Wi, y0p);
    k_post<0><<<gpost, 256, 0, stream>>>(y0p, Wi, wtb, nullptr);
    k_fused<<<gfuse, 256, 0, stream>>>(xbuf, wtb, ypart);
    k_post<1><<<gpost, 256, 0, stream>>>(ypart, Wi, wtb, nullptr);
    k_fused<<<gfuse, 256, 0, stream>>>(xbuf, wtb, ypart);
    k_post<2><<<gpost, 256, 0, stream>>>(ypart, Wi, nullptr, out);
  }
}

// Round 3
// 157.763 us; speedup vs baseline: 5.1673x; 1.4912x over previous
//
#include <hip/hip_runtime.h>
#include <cstdint>
#include <cstddef>

#define BATCH 64
#define NIN   1024
#define CIN   256
#define NC    32
#define NJC   16     // j-blocks per batch (64 j each)
#define JCH   64
#define T_EPS 1e-7f
#define CT_S  72     // cT row stride in u16 (144 B)

typedef __attribute__((ext_vector_type(8))) short short8;   // 8 bf16 = 4 VGPR
typedef __attribute__((ext_vector_type(4))) float floatx4;  // MFMA 16x16 acc

__device__ __forceinline__ unsigned short bf16rne(float f) {
  unsigned int u = __float_as_uint(f);
  u += 0x7FFFu + ((u >> 16) & 1u);
  return (unsigned short)(u >> 16);
}
__device__ __forceinline__ float bf2f(unsigned short h) {
  return __uint_as_float(((unsigned int)h) << 16);
}
// swizzled u16 index into the 64x256 LDS x-tile (16B chunks XOR-permuted per j)
__device__ __forceinline__ int xsw(int j, int c) {
  return j * 256 + ((((c >> 3) ^ (j & 7) ^ ((j >> 3) & 7)) << 3) | (c & 7));
}

union USH {
  unsigned short cT[NC * CT_S]; // 4.5 KB (fused softmax coeffs)
};

// ---- K1: colsum partials + Wi build (b==0). NO xb write -------------------
// grid (jc=16, b=64). x read warms L3 for the two k_fusedf passes.
__global__ __launch_bounds__(256) void k_colsum(const float* __restrict__ x,
                                                const float* __restrict__ W,
                                                unsigned short* __restrict__ Wi,
                                                float* __restrict__ y0p) {
  const int jc = blockIdx.x, b = blockIdx.y, t = threadIdx.x;
  const int jj = t >> 6, c4 = t & 63;
  __shared__ float4 red[4][64];
  const float4* xg = (const float4*)(x + ((size_t)(b * NIN + jc * JCH)) * CIN);
  float4 acc = make_float4(0.f, 0.f, 0.f, 0.f);
  #pragma unroll
  for (int jr = 0; jr < 16; ++jr) {
    int j = jr * 4 + jj;
    float4 v = xg[j * 64 + c4];
    acc.x += v.x; acc.y += v.y; acc.z += v.z; acc.w += v.w;
  }
  red[jj][c4] = acc;
  if (b == 0) {
    // build Wi rows for i = jc*2, jc*2+1 ; thread t <-> c.  Wi[i][c][k] bf16.
    #pragma unroll
    for (int i2 = 0; i2 < 2; ++i2) {
      int i = jc * 2 + i2;
      const float4* wsrc = (const float4*)(W + (size_t)t * 1024 + i * 32);
      unsigned short* wdst = Wi + ((size_t)i * CIN + t) * NC;
      #pragma unroll
      for (int k4 = 0; k4 < 8; ++k4) {
        float4 v = wsrc[k4];
        ushort4 h;
        h.x = bf16rne(v.x); h.y = bf16rne(v.y);
        h.z = bf16rne(v.z); h.w = bf16rne(v.w);
        *(ushort4*)&wdst[k4 * 4] = h;
      }
    }
  }
  __syncthreads();
  if (t < 64) {
    float4 s = red[0][t];
    #pragma unroll
    for (int p = 1; p < 4; ++p) {
      s.x += red[p][t].x; s.y += red[p][t].y;
      s.z += red[p][t].z; s.w += red[p][t].w;
    }
    *(float4*)&y0p[(b * NJC + jc) * CIN + t * 4] = s;
  }
}

// ---- K2: y-reduce -> s = y@W_i -> squash -> wt(bf16) or out ---------------
// grid (i=NC, b=BATCH). MODE 0: yin=y0p fp32 (scale 1/32). MODE 1: yin=ypart
// bf16 [b][jc][i][c], write wt. MODE 2: write out.
template <int MODE>
__global__ __launch_bounds__(256) void k_post(const void* __restrict__ yin,
                                              const unsigned short* __restrict__ Wi,
                                              unsigned short* __restrict__ wtout,
                                              float* __restrict__ outg) {
  const int i = blockIdx.x, b = blockIdx.y, t = threadIdx.x;
  __shared__ float ys[CIN];
  __shared__ float sred[8][32];
  __shared__ float os[NC];
  float a = 0.f;
  if (MODE == 0) {
    const float* y0p = (const float*)yin;
    #pragma unroll
    for (int p = 0; p < NJC; ++p) a += y0p[(b * NJC + p) * CIN + t];
    a *= (1.f / 32.f);
  } else {
    const unsigned short* yp = (const unsigned short*)yin;
    #pragma unroll
    for (int p = 0; p < NJC; ++p)
      a += bf2f(yp[(((size_t)(b * NJC + p)) * NC + i) * CIN + t]);
  }
  ys[t] = a;
  __syncthreads();
  // s[k] partials over c (8 groups x 32 k); rotated c start keeps the
  // ys broadcast reads conflict-free
  const unsigned short* Wis = Wi + (size_t)i * CIN * NC;
  {
    const int k = t & 31, g = t >> 5;
    float ps = 0.f;
    #pragma unroll
    for (int cc = 0; cc < 32; ++cc) {
      int c = g * 32 + ((cc + g * 4) & 31);
      ps += ys[c] * bf2f(Wis[c * NC + k]);
    }
    sred[g][k] = ps;
  }
  __syncthreads();
  const int k = t & 31;
  float s = 0.f;
  #pragma unroll
  for (int g = 0; g < 8; ++g) s += sred[g][k];
  float s2 = s * s;
  #pragma unroll
  for (int m = 1; m < 32; m <<= 1) s2 += __shfl_xor(s2, m);
  float o = s * rsqrtf(s2 + T_EPS);
  if (MODE == 2) {
    if (t < 32) outg[((size_t)b * NC + i) * 32 + t] = o;
  } else {
    if (t < 32) os[t] = o;
    __syncthreads();
    // wt[b,i,c=t] = sum_k os[k] * Wi[i][t][k]  (b128 coalesced)
    float acc = 0.f;
    const short8* wrow = (const short8*)(Wis + (size_t)t * NC);
    #pragma unroll
    for (int k8 = 0; k8 < 4; ++k8) {
      short8 wv = wrow[k8];
      #pragma unroll
      for (int e = 0; e < 8; ++e)
        acc += os[k8 * 8 + e] * bf2f((unsigned short)wv[e]);
    }
    wtout[((size_t)b * NC + i) * CIN + t] = bf16rne(acc);
  }
}

// ---- fused routing iteration core: L = wt@x^T -> softmax(i) -> y = c@x ----
// x tile already resident (swizzled) in xs.
__device__ __forceinline__ void fused_iter(int b, int t,
                                           const unsigned short* xs, USH* u,
                                           const unsigned short* __restrict__ wt,
                                           unsigned short* __restrict__ yo) {
  const int w = t >> 6, l16 = t & 15, q = (t >> 4) & 3;
  const int jloc = w * 16 + l16;
  const unsigned short* wrow = wt + (size_t)b * NC * CIN;
  floatx4 accA0 = {0.f, 0.f, 0.f, 0.f}, accA1 = {0.f, 0.f, 0.f, 0.f};
  #pragma unroll
  for (int ks = 0; ks < 8; ++ks) {
    short8 bx = *(const short8*)&xs[xsw(jloc, ks * 32 + q * 8)];
    short8 a0 = *(const short8*)(wrow + (size_t)l16 * CIN + ks * 32 + q * 8);
    short8 a1 = *(const short8*)(wrow + (size_t)(16 + l16) * CIN + ks * 32 + q * 8);
    accA0 = __builtin_amdgcn_mfma_f32_16x16x32_bf16(a0, bx, accA0, 0, 0, 0);
    accA1 = __builtin_amdgcn_mfma_f32_16x16x32_bf16(a1, bx, accA1, 0, 0, 0);
  }
  {
    float m = accA0[0];
    #pragma unroll
    for (int r = 1; r < 4; ++r) m = fmaxf(m, accA0[r]);
    #pragma unroll
    for (int r = 0; r < 4; ++r) m = fmaxf(m, accA1[r]);
    m = fmaxf(m, __shfl_xor(m, 16));
    m = fmaxf(m, __shfl_xor(m, 32));
    float e0[4], e1[4], s = 0.f;
    #pragma unroll
    for (int r = 0; r < 4; ++r) {
      e0[r] = __expf(accA0[r] - m);
      e1[r] = __expf(accA1[r] - m);
      s += e0[r] + e1[r];
    }
    s += __shfl_xor(s, 16);
    s += __shfl_xor(s, 32);
    float rs = 1.f / s;
    #pragma unroll
    for (int r = 0; r < 4; ++r) {
      u->cT[(q * 4 + r) * CT_S + jloc]      = bf16rne(e0[r] * rs);
      u->cT[(16 + q * 4 + r) * CT_S + jloc] = bf16rne(e1[r] * rs);
    }
  }
  __syncthreads();
  const int cw = w * 64;
  floatx4 accB[2][4];
  #pragma unroll
  for (int h = 0; h < 2; ++h)
    #pragma unroll
    for (int ct = 0; ct < 4; ++ct) accB[h][ct] = (floatx4){0.f, 0.f, 0.f, 0.f};
  #pragma unroll
  for (int ks = 0; ks < 2; ++ks) {
    short8 ca0 = *(const short8*)&u->cT[l16 * CT_S + ks * 32 + q * 8];
    short8 ca1 = *(const short8*)&u->cT[(16 + l16) * CT_S + ks * 32 + q * 8];
    #pragma unroll
    for (int ct = 0; ct < 4; ++ct) {
      const int c = cw + ct * 16 + l16;
      short8 xf;
      #pragma unroll
      for (int e = 0; e < 8; ++e)
        xf[e] = (short)xs[xsw(ks * 32 + q * 8 + e, c)];
      accB[0][ct] = __builtin_amdgcn_mfma_f32_16x16x32_bf16(ca0, xf, accB[0][ct], 0, 0, 0);
      accB[1][ct] = __builtin_amdgcn_mfma_f32_16x16x32_bf16(ca1, xf, accB[1][ct], 0, 0, 0);
    }
  }
  #pragma unroll
  for (int h = 0; h < 2; ++h)
    #pragma unroll
    for (int ct = 0; ct < 4; ++ct)
      #pragma unroll
      for (int r = 0; r < 4; ++r) {
        int i = h * 16 + q * 4 + r;
        int c = cw + ct * 16 + l16;
        yo[i * CIN + c] = bf16rne(accB[h][ct][r]);
      }
}

// ---- K3/K5: fused iteration reading x fp32 (L3-hot), convert in staging ---
__global__ __launch_bounds__(256, 4) void k_fusedf(const float* __restrict__ x,
                                                   const unsigned short* __restrict__ wt,
                                                   unsigned short* __restrict__ ypart) {
  const int jc = blockIdx.x, b = blockIdx.y, t = threadIdx.x;
  __shared__ unsigned short xs[64 * 256];    // 32 KB, swizzled
  __shared__ USH u;
  {
    const int jj = t >> 6, c4 = t & 63;
    const float4* xg = (const float4*)(x + ((size_t)(b * NIN + jc * JCH)) * CIN);
    #pragma unroll
    for (int jr = 0; jr < 16; ++jr) {
      int j = jr * 4 + jj;
      float4 v = xg[j * 64 + c4];
      ushort4 h;
      h.x = bf16rne(v.x); h.y = bf16rne(v.y);
      h.z = bf16rne(v.z); h.w = bf16rne(v.w);
      // c = c4*4: low 3 bits 0 or 4 -> stays inside one 8-elem chunk, xsw-safe
      *(ushort4*)&xs[xsw(j, c4 * 4)] = h;
    }
  }
  __syncthreads();
  fused_iter(b, t, xs, &u, wt, ypart + ((size_t)(b * NJC + jc)) * NC * CIN);
}

// ===========================================================================

extern "C" void kernel_launch(void* const* d_in, const int* in_sizes, int n_in,
                              void* d_out, int out_size, void* d_ws, size_t ws_size,
                              hipStream_t stream) {
  (void)in_sizes; (void)n_in; (void)out_size; (void)ws_size;
  const float* x = (const float*)d_in[0];
  const float* W = (const float*)d_in[1];
  float* out = (float*)d_out;
  char* ws = (char*)d_ws;
  // ws: wt 1MiB @0 | ypart 16MiB @1M | y0p 1MiB @17M | Wi 512KiB @18M
  unsigned short* wtb   = (unsigned short*)ws;
  unsigned short* ypart = (unsigned short*)(ws + (1ull << 20));
  float*          y0p   = (float*)(ws + (17ull << 20));
  unsigned short* Wi    = (unsigned short*)(ws + (18ull << 20));

  dim3 gfuse(NJC, BATCH);     // (16, 64)
  dim3 gpost(NC, BATCH);      // (32, 64)
  k_colsum<<<gfuse, 256, 0, stream>>>(x, W, Wi, y0p);
  k_post<0><<<gpost, 256, 0, stream>>>(y0p, Wi, wtb, nullptr);    // iter 0
  k_fusedf<<<gfuse, 256, 0, stream>>>(x, wtb, ypart);             // iter 1
  k_post<1><<<gpost, 256, 0, stream>>>(ypart, Wi, wtb, nullptr);
  k_fusedf<<<gfuse, 256, 0, stream>>>(x, wtb, ypart);             // iter 2
  k_post<2><<<gpost, 256, 0, stream>>>(ypart, Wi, nullptr, out);
}